// Round 2
// baseline (91.563 us; speedup 1.0000x reference)
//
#include <hip/hip_runtime.h>

#define NROWS 500000
#define NCOLS 80
#define NV (NROWS * NCOLS / 4)   // float4 chunks in logits

// Stable pieces from e = exp(-|x|):
//   p  = sigmoid(x)  = x>=0 ? 1/(1+e) : 1 - 1/(1+e)
//   sp = softplus(x) = max(x,0) + log(1+e)
__device__ __forceinline__ float base_term(float x) {
    float ax = fabsf(x);
    float e  = __expf(-ax);
    float rt = __builtin_amdgcn_rcpf(1.0f + e);   // raw v_rcp_f32
    float p  = (x >= 0.0f) ? rt : 1.0f - rt;
    float sp = fmaxf(x, 0.0f) + __logf(1.0f + e);
    return sp - p;                                // caller scales by 0.75
}

// ---------------------------------------------------------------------------
// Kernel 1: (a) M = max iou over fg rows (4 MB scan, atomicMax as uint —
// all candidates >= 0), (b) sum of M-independent base term over all 40M
// elements (160 MB pure stream, no targets, no division, no branches).
// ---------------------------------------------------------------------------
__global__ void base_kernel(const float4* __restrict__ logits4,
                            const float2* __restrict__ targets,
                            float* __restrict__ m_out,
                            float* __restrict__ out) {
    unsigned tid = blockIdx.x * blockDim.x + threadIdx.x;
    unsigned stride = gridDim.x * blockDim.x;
    int lane = threadIdx.x & 63;
    int wid  = threadIdx.x >> 6;
    __shared__ float red[4];

    // --- max pass (1 iteration per thread at this grid size) ---
    float vmax = 0.0f;
    for (unsigned i = tid; i < (unsigned)NROWS; i += stride) {
        float2 t = targets[i];
        if ((int)t.x >= 1) vmax = fmaxf(vmax, t.y);
    }
    #pragma unroll
    for (int off = 32; off > 0; off >>= 1)
        vmax = fmaxf(vmax, __shfl_xor(vmax, off));
    if (lane == 0) red[wid] = vmax;
    __syncthreads();
    if (threadIdx.x == 0) {
        float b = fmaxf(fmaxf(red[0], red[1]), fmaxf(red[2], red[3]));
        atomicMax((unsigned int*)m_out, __float_as_uint(b));
    }
    __syncthreads();   // before reusing red[]

    // --- base sum (pure stream) ---
    float acc = 0.0f;
    for (unsigned v = tid; v < (unsigned)NV; v += stride) {
        float4 x4 = logits4[v];
        acc += base_term(x4.x) + base_term(x4.y)
             + base_term(x4.z) + base_term(x4.w);
    }
    #pragma unroll
    for (int off = 32; off > 0; off >>= 1)
        acc += __shfl_xor(acc, off);
    if (lane == 0) red[wid] = acc;
    __syncthreads();
    if (threadIdx.x == 0) {
        float b = (red[0] + red[1]) + (red[2] + red[3]);
        atomicAdd(out, 0.75f * b);
    }
}

// ---------------------------------------------------------------------------
// Kernel 2: per fg row, replace the base term at column c with the full
// pos/neg term: add  (full - 0.75*(sp-p)).  Gathers 1 logit per fg row —
// logits is L3-resident (160 MB < 256 MB) right after kernel 1.
// ---------------------------------------------------------------------------
__global__ void correction_kernel(const float* __restrict__ logits,
                                  const float2* __restrict__ targets,
                                  const float* __restrict__ m_ptr,
                                  float* __restrict__ out) {
    const float invM = __builtin_amdgcn_rcpf(m_ptr[0]);
    unsigned tid = blockIdx.x * blockDim.x + threadIdx.x;
    unsigned stride = gridDim.x * blockDim.x;
    float acc = 0.0f;
    for (unsigned r = tid; r < (unsigned)NROWS; r += stride) {
        float2 t = targets[r];
        int c = (int)t.x - 1;
        if (c >= 0) {
            float x  = logits[r * NCOLS + c];
            float L  = t.y * invM;
            float ax = fabsf(x);
            float e  = __expf(-ax);
            float rt = __builtin_amdgcn_rcpf(1.0f + e);
            float p  = (x >= 0.0f) ? rt : 1.0f - rt;
            float sp = fmaxf(x, 0.0f) + __logf(1.0f + e);
            float full;
            if (p <= L) {
                float spn = sp - x;                       // softplus(-x)
                full = 0.25f * (spn * L + (p - L));
            } else {
                full = 0.75f * (sp * (1.0f - L) + (L - p));
            }
            acc += full - 0.75f * (sp - p);
        }
    }
    #pragma unroll
    for (int off = 32; off > 0; off >>= 1)
        acc += __shfl_xor(acc, off);
    __shared__ float red[4];
    int lane = threadIdx.x & 63;
    int wid  = threadIdx.x >> 6;
    if (lane == 0) red[wid] = acc;
    __syncthreads();
    if (threadIdx.x == 0) {
        float b = (red[0] + red[1]) + (red[2] + red[3]);
        atomicAdd(out, b);
    }
}

extern "C" void kernel_launch(void* const* d_in, const int* in_sizes, int n_in,
                              void* d_out, int out_size, void* d_ws, size_t ws_size,
                              hipStream_t stream) {
    const float* logits  = (const float*)d_in[0];   // (N, C) f32
    const float* targets = (const float*)d_in[1];   // (N, 2) f32
    float* out = (float*)d_out;                     // scalar f32
    float* m   = (float*)d_ws;                      // 4B scratch: global max

    hipMemsetAsync(out, 0, sizeof(float), stream);
    hipMemsetAsync(m,   0, sizeof(float), stream);

    base_kernel<<<2048, 256, 0, stream>>>((const float4*)logits,
                                          (const float2*)targets, m, out);
    correction_kernel<<<1024, 256, 0, stream>>>(logits, (const float2*)targets,
                                                m, out);
}

// Round 3
// 54.743 us; speedup vs baseline: 1.6726x; 1.6726x over previous
//
#include <hip/hip_runtime.h>

#define NROWS 500000
#define NCOLS 80
#define RPB   80                    // rows per K3 block
#define TPB3  320                   // K3 threads: 16 rows x 20 chunks per slab
#define SLABS 5                     // 5 slabs x 16 rows = 80 rows
#define NBLK3 (NROWS / RPB)         // 6250, exact
#define MAXBLK 256                  // K1 grid

// d_ws float layout
#define WS_INVM 0                   // [0]      : 1/M
#define WS_MAXP 16                  // [16..272): K1 per-block maxes
#define WS_PART 512                 // [512..512+6250): K3 per-block partials

// ---------------------------------------------------------------------------
// K1: per-block max of iou over fg rows (coalesced float2 scan, no atomics)
// ---------------------------------------------------------------------------
__global__ void max_kernel(const float2* __restrict__ targets,
                           float* __restrict__ maxp) {
    unsigned tid = blockIdx.x * blockDim.x + threadIdx.x;
    unsigned stride = gridDim.x * blockDim.x;
    float vmax = 0.0f;
    for (unsigned i = tid; i < (unsigned)NROWS; i += stride) {
        float2 t = targets[i];
        if ((int)t.x >= 1) vmax = fmaxf(vmax, t.y);
    }
    #pragma unroll
    for (int off = 32; off > 0; off >>= 1)
        vmax = fmaxf(vmax, __shfl_xor(vmax, off));
    __shared__ float red[4];
    int lane = threadIdx.x & 63, wid = threadIdx.x >> 6;
    if (lane == 0) red[wid] = vmax;
    __syncthreads();
    if (threadIdx.x == 0)
        maxp[blockIdx.x] = fmaxf(fmaxf(red[0], red[1]), fmaxf(red[2], red[3]));
}

// ---------------------------------------------------------------------------
// K2: single block reduces the 256 partial maxes -> invM
// ---------------------------------------------------------------------------
__global__ void invm_kernel(const float* __restrict__ maxp,
                            float* __restrict__ invm) {
    float v = maxp[threadIdx.x];             // 256 threads, 256 entries
    #pragma unroll
    for (int off = 32; off > 0; off >>= 1)
        v = fmaxf(v, __shfl_xor(v, off));
    __shared__ float red[4];
    int lane = threadIdx.x & 63, wid = threadIdx.x >> 6;
    if (lane == 0) red[wid] = v;
    __syncthreads();
    if (threadIdx.x == 0) {
        float m = fmaxf(fmaxf(red[0], red[1]), fmaxf(red[2], red[3]));
        invm[0] = 1.0f / m;
    }
}

// ---------------------------------------------------------------------------
// K3: main stream. Block b owns rows [80b, 80b+80): 5 slabs of 16 rows.
// Thread t: chunk q = t%20, row-in-slab rl = t/20.  Chunk address per slab
// = b*1600 + s*320 + t  -> contiguous 5120B per slab, fully coalesced.
// targets for the 80 rows staged once in LDS. fg element handled inline.
// Per-block partial written to ws (no atomics).
// ---------------------------------------------------------------------------
__global__ void __launch_bounds__(TPB3)
main_kernel(const float4* __restrict__ logits4,
            const float2* __restrict__ targets,
            const float* __restrict__ invm_ptr,
            float* __restrict__ partials) {
    __shared__ float2 t2s[RPB];
    const unsigned t = threadIdx.x;
    const unsigned b = blockIdx.x;
    if (t < RPB) t2s[t] = targets[b * RPB + t];
    const float invM = invm_ptr[0];
    const unsigned rl = t / 20u;             // row within slab (0..15)
    const int j0 = (int)(t - rl * 20u) * 4;  // first column of this chunk
    __syncthreads();

    float acc_base = 0.0f;                   // sum of (sp - p), scaled later
    float acc_corr = 0.0f;                   // fg corrections
    const unsigned base = b * (RPB * NCOLS / 4);
    #pragma unroll
    for (int s = 0; s < SLABS; ++s) {
        float4 x4 = logits4[base + (unsigned)s * TPB3 + t];
        float2 tt = t2s[s * 16 + rl];
        int   c = (int)tt.x - 1;
        float L = tt.y * invM;
        float xs[4] = {x4.x, x4.y, x4.z, x4.w};
        #pragma unroll
        for (int k = 0; k < 4; ++k) {
            float x  = xs[k];
            float ax = fabsf(x);
            float e  = __expf(-ax);
            float r  = __builtin_amdgcn_rcpf(1.0f + e);
            float p  = (x >= 0.0f) ? r : 1.0f - r;
            float sp = fmaxf(x, 0.0f) + __logf(1.0f + e);
            float bt = sp - p;
            acc_base += bt;
            if (j0 + k == c) {               // the single fg element this row
                float full;
                if (p <= L) {
                    float spn = sp - x;      // softplus(-x)
                    full = 0.25f * (spn * L + (p - L));
                } else {
                    full = 0.75f * (sp * (1.0f - L) + (L - p));
                }
                acc_corr += full - 0.75f * bt;
            }
        }
    }
    float acc = 0.75f * acc_base + acc_corr;
    #pragma unroll
    for (int off = 32; off > 0; off >>= 1)
        acc += __shfl_xor(acc, off);
    __shared__ float red[TPB3 / 64];
    int lane = threadIdx.x & 63, wid = threadIdx.x >> 6;
    if (lane == 0) red[wid] = acc;
    __syncthreads();
    if (threadIdx.x == 0) {
        float s = 0.0f;
        #pragma unroll
        for (int w = 0; w < TPB3 / 64; ++w) s += red[w];
        partials[b] = s;
    }
}

// ---------------------------------------------------------------------------
// K4: single block sums the 6250 block partials -> out[0]
// ---------------------------------------------------------------------------
__global__ void final_kernel(const float* __restrict__ partials,
                             float* __restrict__ out) {
    float acc = 0.0f;
    for (unsigned i = threadIdx.x; i < (unsigned)NBLK3; i += blockDim.x)
        acc += partials[i];
    #pragma unroll
    for (int off = 32; off > 0; off >>= 1)
        acc += __shfl_xor(acc, off);
    __shared__ float red[4];
    int lane = threadIdx.x & 63, wid = threadIdx.x >> 6;
    if (lane == 0) red[wid] = acc;
    __syncthreads();
    if (threadIdx.x == 0)
        out[0] = (red[0] + red[1]) + (red[2] + red[3]);
}

extern "C" void kernel_launch(void* const* d_in, const int* in_sizes, int n_in,
                              void* d_out, int out_size, void* d_ws, size_t ws_size,
                              hipStream_t stream) {
    const float* logits  = (const float*)d_in[0];   // (N, C) f32
    const float* targets = (const float*)d_in[1];   // (N, 2) f32
    float* out = (float*)d_out;
    float* ws  = (float*)d_ws;

    // every ws/out location is written before read each call -> no memsets
    max_kernel <<<MAXBLK, 256, 0, stream>>>((const float2*)targets, ws + WS_MAXP);
    invm_kernel<<<1,      256, 0, stream>>>(ws + WS_MAXP, ws + WS_INVM);
    main_kernel<<<NBLK3, TPB3, 0, stream>>>((const float4*)logits,
                                            (const float2*)targets,
                                            ws + WS_INVM, ws + WS_PART);
    final_kernel<<<1,     256, 0, stream>>>(ws + WS_PART, out);
}